// Round 11
// baseline (37.583 us; speedup 1.0000x reference)
//
#include <hip/hip_runtime.h>
#include <hip/hip_bf16.h>

typedef __bf16 bf16x8 __attribute__((ext_vector_type(8)));
typedef float  f32x4  __attribute__((ext_vector_type(4)));

static constexpr int NB = 8;
static constexpr int S  = 2048;
static constexpr int T  = 2048;
static constexpr int D  = 128;

// ws layout: wsrc[16384 rows][16 uint4], wtar[16384 rows][16 uint4]  (8 MB)
// Each row: 128 bf16 (normalized, mask-folded), slot q stored at (q ^ (row&7))
// == the exact LDS image the GEMM wants (global_load_lds copies linearly).

__device__ __forceinline__ void g2l(const uint4* g, uint4* l) {
    __builtin_amdgcn_global_load_lds((const __attribute__((address_space(1))) void*)g,
                                     (__attribute__((address_space(3))) void*)l, 16, 0, 0);
}

// ---------------- pass 1: normalize + mask-zero + bf16 + swizzled image ----------------
// Full chip: 256 blocks x 512 threads, 4 threads per row (32 floats each).
// Input reads are nontemporal: single-use f32 must not pollute L2/L3.
__global__ __launch_bounds__(512, 2)
void prep(const float* __restrict__ src, const float* __restrict__ tar,
          const int* __restrict__ ms, const int* __restrict__ mt,
          uint4* __restrict__ ws)
{
    const int tid  = threadIdx.x;
    const int qid  = blockIdx.x * 512 + tid;    // quarter-row id, 0..131071
    const int row  = qid >> 2;                  // 0..32767  (src rows then tar rows)
    const int q    = qid & 3;
    const bool isT = row >= NB * S;
    const int  r   = isT ? row - NB * S : row;  // 0..16383 within src/tar
    const float* p = (isT ? tar : src) + (size_t)r * D + q * 32;
    const int   mk = (isT ? mt : ms)[r];
    uint4*      wp = ws + (size_t)row * 16;

    f32x4 v[8];
    float ss = 0.f;
    if (mk) {
        #pragma unroll
        for (int j = 0; j < 8; ++j) {
            v[j] = __builtin_nontemporal_load((const f32x4*)p + j);
            ss += v[j][0] * v[j][0] + v[j][1] * v[j][1] + v[j][2] * v[j][2] + v[j][3] * v[j][3];
        }
    } else {
        #pragma unroll
        for (int j = 0; j < 8; ++j) v[j] = f32x4{0.f, 0.f, 0.f, 0.f};
    }
    ss += __shfl_xor(ss, 1);                    // 4-lane group reduce (lanes of one row)
    ss += __shfl_xor(ss, 2);
    const float sc = mk ? (1.0f / fmaxf(sqrtf(ss), 1e-12f)) : 0.0f;

    #pragma unroll
    for (int i = 0; i < 4; ++i) {
        const f32x4 u0 = v[2 * i], u1 = v[2 * i + 1];
        bf16x8 t;
        t[0] = (__bf16)(u0[0] * sc); t[1] = (__bf16)(u0[1] * sc);
        t[2] = (__bf16)(u0[2] * sc); t[3] = (__bf16)(u0[3] * sc);
        t[4] = (__bf16)(u1[0] * sc); t[5] = (__bf16)(u1[1] * sc);
        t[6] = (__bf16)(u1[2] * sc); t[7] = (__bf16)(u1[3] * sc);
        wp[(q * 4 + i) ^ (r & 7)] = __builtin_bit_cast(uint4, t);
    }
}

// ---------------- pass 2: tiled GEMM, 4 tiles per block, one generation ----------------
// Grid 512 = 2 blocks/CU, all co-resident. Block (b, ts, pp): S-panel ts staged
// ONCE; T-panels pp*4..pp*4+3 processed with rolling prefetch. The 16 blocks
// per XCD sharing a T-panel group touch each panel concurrently -> L2 reuse.
__global__ __launch_bounds__(512, 4)
void gemm(const uint4* __restrict__ ws, float* __restrict__ out)
{
    __shared__ uint4 ldsS[128 * 16];   // 32 KB  src panel (B operand, 128 s-rows)
    __shared__ uint4 ldsT[128 * 16];   // 32 KB  tar panel (A operand, 128 t-rows)

    const uint4* wsrc = ws;
    const uint4* wtar = ws + (size_t)NB * S * 16;

    const int blk = blockIdx.x;        // 0..511 ; round-robin => b == XCD id
    const int b   = blk & 7;
    const int j   = blk >> 3;          // 0..63
    const int ts  = j >> 2;            // 0..15  source tile (128 rows)
    const int pp  = j & 3;             // 0..3   target-panel group (4 x 128 rows)

    const int tid  = threadIdx.x;
    const int lane = tid & 63;
    const int w    = tid >> 6;
    const int wt   = w & 1;            // 0..1  t-half (64 t-rows)
    const int wsp  = w >> 1;           // 0..3  s-quarter (32 s-rows)
    const int r16  = lane & 15;
    const int kg   = lane >> 4;        // 0..3
    const int swz  = r16 & 7;

    const uint4* gs      = wsrc + ((size_t)(b * S + ts * 128)) * 16;
    const uint4* gt_base = wtar + ((size_t)(b * T + pp * 4 * 128)) * 16;

    // prologue stage: S panel + first T panel (linear copy of pre-swizzled image)
    #pragma unroll
    for (int i = 0; i < 4; ++i) {
        const int idx = i * 512 + tid;
        g2l(gs + idx,      &ldsS[i * 512 + w * 64]);
        g2l(gt_base + idx, &ldsT[i * 512 + w * 64]);
    }
    __syncthreads();

    f32x4 acc[4][2];

    #pragma unroll
    for (int tile = 0; tile < 4; ++tile) {
        #pragma unroll
        for (int m = 0; m < 4; ++m)
            #pragma unroll
            for (int n = 0; n < 2; ++n)
                acc[m][n] = f32x4{0.f, 0.f, 0.f, 0.f};

        #pragma unroll
        for (int ks = 0; ks < 4; ++ks) {          // K = 4 * 32
            bf16x8 at[4], bs[2];
            #pragma unroll
            for (int m = 0; m < 4; ++m) {
                const int rl = wt * 64 + m * 16 + r16;
                at[m] = __builtin_bit_cast(bf16x8, ldsT[rl * 16 + ((ks * 4 + kg) ^ swz)]);
            }
            #pragma unroll
            for (int n = 0; n < 2; ++n) {
                const int rl = wsp * 32 + n * 16 + r16;
                bs[n] = __builtin_bit_cast(bf16x8, ldsS[rl * 16 + ((ks * 4 + kg) ^ swz)]);
            }
            #pragma unroll
            for (int m = 0; m < 4; ++m)
                #pragma unroll
                for (int n = 0; n < 2; ++n)
                    acc[m][n] = __builtin_amdgcn_mfma_f32_16x16x32_bf16(at[m], bs[n], acc[m][n], 0, 0, 0);
        }

        if (tile < 3) {
            __syncthreads();                       // all waves done reading ldsT
            const uint4* gt = gt_base + (size_t)(tile + 1) * 128 * 16;
            #pragma unroll
            for (int i = 0; i < 4; ++i)            // prefetch next tar panel (4 loads)
                g2l(gt + i * 512 + tid, &ldsT[i * 512 + w * 64]);
            __builtin_amdgcn_sched_barrier(0);     // pin: loads issued before stores
        }

        // epilogue: ReLU + f32x4 stores (norms & masks folded in prep)
        const int ttc = pp * 4 + tile;
        #pragma unroll
        for (int m = 0; m < 4; ++m) {
            const int tl = wt * 64 + m * 16 + kg * 4;
            #pragma unroll
            for (int n = 0; n < 2; ++n) {
                const int sl = wsp * 32 + n * 16 + r16;
                const f32x4 a = acc[m][n];
                f32x4 o;
                o[0] = fmaxf(a[0], 0.f);
                o[1] = fmaxf(a[1], 0.f);
                o[2] = fmaxf(a[2], 0.f);
                o[3] = fmaxf(a[3], 0.f);
                float* po = out + ((size_t)(b * S + ts * 128 + sl)) * T + (size_t)ttc * 128 + tl;
                *(f32x4*)po = o;
            }
        }

        if (tile < 3) {
            // wait down to 8 outstanding: retires the 4 prefetch loads (issued
            // before this tile's 8 stores); stores keep flying under the barrier
            asm volatile("s_waitcnt vmcnt(8)" ::: "memory");
            __builtin_amdgcn_s_barrier();
            __builtin_amdgcn_sched_barrier(0);
        }
    }
}

extern "C" void kernel_launch(void* const* d_in, const int* in_sizes, int n_in,
                              void* d_out, int out_size, void* d_ws, size_t ws_size,
                              hipStream_t stream) {
    const float* src    = (const float*)d_in[0];
    const float* tar    = (const float*)d_in[1];
    const int*   mask_s = (const int*)d_in[2];
    const int*   mask_t = (const int*)d_in[3];
    float*       out    = (float*)d_out;
    uint4*       ws     = (uint4*)d_ws;

    hipLaunchKernelGGL(prep, dim3(256), dim3(512), 0, stream, src, tar, mask_s, mask_t, ws);
    hipLaunchKernelGGL(gemm, dim3(512), dim3(512), 0, stream, ws, out);
}

// Round 12
// 35.024 us; speedup vs baseline: 1.0731x; 1.0731x over previous
//
#include <hip/hip_runtime.h>
#include <hip/hip_bf16.h>

typedef __bf16 bf16x8 __attribute__((ext_vector_type(8)));
typedef float  f32x4  __attribute__((ext_vector_type(4)));

static constexpr int NB = 8;
static constexpr int S  = 2048;
static constexpr int T  = 2048;
static constexpr int D  = 128;

// ws layout: wsrc[16384 rows][16 uint4], wtar[16384 rows][16 uint4]  (8 MB)
// Each row: 128 bf16 (normalized, mask-folded), slot q stored at (q ^ (row&7))
// == the exact LDS image the GEMM wants (global_load_lds copies linearly).

__device__ __forceinline__ void g2l(const uint4* g, uint4* l) {
    __builtin_amdgcn_global_load_lds((const __attribute__((address_space(1))) void*)g,
                                     (__attribute__((address_space(3))) void*)l, 16, 0, 0);
}

// ---------------- pass 1: normalize + mask-zero + bf16 + swizzled image ----------------
// Full chip: 256 blocks x 512 threads, 4 threads per row (32 floats each).
__global__ __launch_bounds__(512, 2)
void prep(const float* __restrict__ src, const float* __restrict__ tar,
          const int* __restrict__ ms, const int* __restrict__ mt,
          uint4* __restrict__ ws)
{
    const int tid  = threadIdx.x;
    const int qid  = blockIdx.x * 512 + tid;    // quarter-row id, 0..131071
    const int row  = qid >> 2;                  // 0..32767  (src rows then tar rows)
    const int q    = qid & 3;
    const bool isT = row >= NB * S;
    const int  r   = isT ? row - NB * S : row;  // 0..16383 within src/tar
    const float* p = (isT ? tar : src) + (size_t)r * D + q * 32;
    const int   mk = (isT ? mt : ms)[r];
    uint4*      wp = ws + (size_t)row * 16;

    float4 v[8];
    float ss = 0.f;
    if (mk) {
        #pragma unroll
        for (int j = 0; j < 8; ++j) {
            v[j] = ((const float4*)p)[j];
            ss += v[j].x * v[j].x + v[j].y * v[j].y + v[j].z * v[j].z + v[j].w * v[j].w;
        }
    } else {
        #pragma unroll
        for (int j = 0; j < 8; ++j) v[j] = float4{0.f, 0.f, 0.f, 0.f};
    }
    ss += __shfl_xor(ss, 1);                    // 4-lane group reduce (lanes of one row)
    ss += __shfl_xor(ss, 2);
    const float sc = mk ? (1.0f / fmaxf(sqrtf(ss), 1e-12f)) : 0.0f;

    #pragma unroll
    for (int i = 0; i < 4; ++i) {
        const float4 u0 = v[2 * i], u1 = v[2 * i + 1];
        bf16x8 t;
        t[0] = (__bf16)(u0.x * sc); t[1] = (__bf16)(u0.y * sc);
        t[2] = (__bf16)(u0.z * sc); t[3] = (__bf16)(u0.w * sc);
        t[4] = (__bf16)(u1.x * sc); t[5] = (__bf16)(u1.y * sc);
        t[6] = (__bf16)(u1.z * sc); t[7] = (__bf16)(u1.w * sc);
        wp[(q * 4 + i) ^ (r & 7)] = __builtin_bit_cast(uint4, t);
    }
}

// ---------------- pass 2: tiled GEMM, R9 grid (1024 blocks, 128s x 256t) ----------------
// S-operand lives in registers (loaded once per block from the pre-swizzled ws
// image). Freed LDS is a 32KB transpose buffer: finalized f32 goes acc->ldsX
// (XOR swizzled) -> cooperative stores, each wave-instr = 2 rows x 512B
// contiguous (vs 16 rows x 64B in R9). Epilogue barriers are raw s_barrier +
// lgkmcnt-only waits so global stores never drain inside the tile loop.
__global__ __launch_bounds__(512, 4)
void gemm(const uint4* __restrict__ ws, float* __restrict__ out)
{
    __shared__ uint4 ldsT[128 * 16];   // 32 KB  tar panel (A operand, 128 t-rows)
    __shared__ uint4 ldsX[64 * 32];    // 32 KB  f32 epilogue buffer (64 rows x 512B)

    const uint4* wsrc = ws;
    const uint4* wtar = ws + (size_t)NB * S * 16;

    const int blk = blockIdx.x;        // 0..1023 ; round-robin => b == XCD id
    const int b   = blk & 7;
    const int j   = blk >> 3;          // 0..127
    const int ts  = j >> 3;            // 0..15  source tile (128 rows)
    const int tp  = j & 7;             // 0..7   target pair (2 x 128 rows)

    const int tid  = threadIdx.x;
    const int lane = tid & 63;
    const int w    = tid >> 6;
    const int wt   = w & 1;            // 0..1  t-half (64 t-rows)
    const int wsp  = w >> 1;           // 0..3  s-quarter (32 s-rows)
    const int r16  = lane & 15;
    const int kg   = lane >> 4;        // 0..3
    const int swz  = r16 & 7;

    // ---- B operand (src rows) directly into registers, once per block ----
    bf16x8 bregs[2][4];
    #pragma unroll
    for (int n = 0; n < 2; ++n)
        #pragma unroll
        for (int ks = 0; ks < 4; ++ks) {
            const int R = b * S + ts * 128 + wsp * 32 + n * 16 + r16;
            bregs[n][ks] = __builtin_bit_cast(bf16x8, wsrc[(size_t)R * 16 + ((ks * 4 + kg) ^ swz)]);
        }

    // ---- stage first T panel ----
    const uint4* gt0 = wtar + ((size_t)(b * T + tp * 256)) * 16;
    #pragma unroll
    for (int i = 0; i < 4; ++i)
        g2l(gt0 + i * 512 + tid, &ldsT[i * 512 + w * 64]);
    asm volatile("s_waitcnt vmcnt(0)" ::: "memory");
    __builtin_amdgcn_s_barrier();
    __builtin_amdgcn_sched_barrier(0);

    f32x4 acc[4][2];

    #pragma unroll
    for (int tile = 0; tile < 2; ++tile) {
        #pragma unroll
        for (int m = 0; m < 4; ++m)
            #pragma unroll
            for (int n = 0; n < 2; ++n)
                acc[m][n] = f32x4{0.f, 0.f, 0.f, 0.f};

        #pragma unroll
        for (int ks = 0; ks < 4; ++ks) {          // K = 4 * 32
            bf16x8 at[4];
            #pragma unroll
            for (int m = 0; m < 4; ++m) {
                const int rl = wt * 64 + m * 16 + r16;
                at[m] = __builtin_bit_cast(bf16x8, ldsT[rl * 16 + ((ks * 4 + kg) ^ swz)]);
            }
            #pragma unroll
            for (int m = 0; m < 4; ++m)
                #pragma unroll
                for (int n = 0; n < 2; ++n)
                    acc[m][n] = __builtin_amdgcn_mfma_f32_16x16x32_bf16(at[m], bregs[n][ks], acc[m][n], 0, 0, 0);
        }

        if (tile == 0) {
            __syncthreads();                       // all waves done reading ldsT (nothing in flight -> cheap)
            const uint4* gt1 = gt0 + 128 * 16;
            #pragma unroll
            for (int i = 0; i < 4; ++i)            // prefetch next tar panel (4 loads)
                g2l(gt1 + i * 512 + tid, &ldsT[i * 512 + w * 64]);
            __builtin_amdgcn_sched_barrier(0);     // pin: loads issued before stores
        }

        // ---- epilogue: acc -> ldsX (64-row halves) -> 2rows x 512B wave stores ----
        const int ttc = tp * 2 + tile;
        #pragma unroll
        for (int h = 0; h < 2; ++h) {
            if ((wsp >> 1) == h) {                 // waves owning s-rows [h*64, h*64+64)
                #pragma unroll
                for (int m = 0; m < 4; ++m)
                    #pragma unroll
                    for (int n = 0; n < 2; ++n) {
                        const int lrow = (wsp & 1) * 32 + n * 16 + r16;   // 0..63
                        const int col  = wt * 16 + m * 4 + kg;            // 0..31 (f32x4 slots)
                        const f32x4 a = acc[m][n];
                        f32x4 o;
                        o[0] = fmaxf(a[0], 0.f);
                        o[1] = fmaxf(a[1], 0.f);
                        o[2] = fmaxf(a[2], 0.f);
                        o[3] = fmaxf(a[3], 0.f);
                        ldsX[lrow * 32 + (col ^ (lrow & 31))] = __builtin_bit_cast(uint4, o);
                    }
            }
            asm volatile("s_waitcnt lgkmcnt(0)" ::: "memory");   // ds_writes visible
            __builtin_amdgcn_s_barrier();
            __builtin_amdgcn_sched_barrier(0);

            #pragma unroll
            for (int it = 0; it < 4; ++it) {       // 64 rows x 32 uint4 cooperative store
                const int flat = it * 512 + tid;   // 0..2047
                const int row  = flat >> 5;        // 0..63
                const int col  = flat & 31;
                const uint4 v = ldsX[row * 32 + (col ^ (row & 31))];
                float* po = out + ((size_t)(b * S + ts * 128 + h * 64 + row)) * T
                                + (size_t)ttc * 128 + col * 4;
                *(f32x4*)po = __builtin_bit_cast(f32x4, v);
            }

            // ldsX reads done before next half overwrites; stores stay in flight
            asm volatile("s_waitcnt lgkmcnt(0)" ::: "memory");
            if (tile == 0 && h == 1)
                asm volatile("s_waitcnt vmcnt(8)" ::: "memory");  // retire the 4 g2l (8 younger stores ok)
            __builtin_amdgcn_s_barrier();
            __builtin_amdgcn_sched_barrier(0);
        }
    }
}

extern "C" void kernel_launch(void* const* d_in, const int* in_sizes, int n_in,
                              void* d_out, int out_size, void* d_ws, size_t ws_size,
                              hipStream_t stream) {
    const float* src    = (const float*)d_in[0];
    const float* tar    = (const float*)d_in[1];
    const int*   mask_s = (const int*)d_in[2];
    const int*   mask_t = (const int*)d_in[3];
    float*       out    = (float*)d_out;
    uint4*       ws     = (uint4*)d_ws;

    hipLaunchKernelGGL(prep, dim3(256), dim3(512), 0, stream, src, tar, mask_s, mask_t, ws);
    hipLaunchKernelGGL(gemm, dim3(1024), dim3(512), 0, stream, ws, out);
}

// Round 13
// 33.645 us; speedup vs baseline: 1.1170x; 1.0410x over previous
//
#include <hip/hip_runtime.h>
#include <hip/hip_bf16.h>

typedef __bf16 bf16x8 __attribute__((ext_vector_type(8)));
typedef float  f32x4  __attribute__((ext_vector_type(4)));

static constexpr int NB = 8;
static constexpr int S  = 2048;
static constexpr int T  = 2048;
static constexpr int D  = 128;

// ws layout: wsrc[16384 rows][16 uint4], wtar[16384 rows][16 uint4]  (8 MB)
// Each row: 128 bf16 (normalized, mask-folded), slot q stored at (q ^ (row&7))
// == the exact LDS image the GEMM wants (global_load_lds copies linearly).

__device__ __forceinline__ void g2l(const uint4* g, uint4* l) {
    __builtin_amdgcn_global_load_lds((const __attribute__((address_space(1))) void*)g,
                                     (__attribute__((address_space(3))) void*)l, 16, 0, 0);
}

// ---------------- pass 1: normalize + mask-zero + bf16 + swizzled image ----------------
// XCD-local ownership: block p preps batch (p&7). With round-robin block->XCD
// dispatch, batch b's ws image is written on XCD b — the same XCD whose gemm
// blocks (blk&7 == b) re-read it -> staging reads hit dirty-local L2, not fabric.
__global__ __launch_bounds__(512, 2)
void prep(const float* __restrict__ src, const float* __restrict__ tar,
          const int* __restrict__ ms, const int* __restrict__ mt,
          uint4* __restrict__ ws)
{
    const int tid   = threadIdx.x;
    const int p     = blockIdx.x;               // 0..255
    const int b     = p & 7;                    // batch == XCD (round-robin)
    const int chunk = p >> 3;                   // 0..31
    const int lr    = chunk * 128 + (tid >> 2); // 0..4095 batch-local row (src then tar)
    const int q     = tid & 3;                  // quarter-row
    const bool isT  = lr >= 2048;
    const int  r    = b * 2048 + (lr & 2047);   // global row within src/tar
    const float* pp = (isT ? tar : src) + (size_t)r * D + q * 32;
    const int   mk  = (isT ? mt : ms)[r];
    uint4*      wp  = ws + ((size_t)(isT ? NB * S : 0) + r) * 16;

    float4 v[8];
    float ss = 0.f;
    if (mk) {
        #pragma unroll
        for (int j = 0; j < 8; ++j) {
            v[j] = ((const float4*)pp)[j];
            ss += v[j].x * v[j].x + v[j].y * v[j].y + v[j].z * v[j].z + v[j].w * v[j].w;
        }
    } else {
        #pragma unroll
        for (int j = 0; j < 8; ++j) v[j] = float4{0.f, 0.f, 0.f, 0.f};
    }
    ss += __shfl_xor(ss, 1);                    // 4-lane group reduce (lanes of one row)
    ss += __shfl_xor(ss, 2);
    const float sc = mk ? (1.0f / fmaxf(sqrtf(ss), 1e-12f)) : 0.0f;

    #pragma unroll
    for (int i = 0; i < 4; ++i) {
        const float4 u0 = v[2 * i], u1 = v[2 * i + 1];
        bf16x8 t;
        t[0] = (__bf16)(u0.x * sc); t[1] = (__bf16)(u0.y * sc);
        t[2] = (__bf16)(u0.z * sc); t[3] = (__bf16)(u0.w * sc);
        t[4] = (__bf16)(u1.x * sc); t[5] = (__bf16)(u1.y * sc);
        t[6] = (__bf16)(u1.z * sc); t[7] = (__bf16)(u1.w * sc);
        wp[(q * 4 + i) ^ (r & 7)] = __builtin_bit_cast(uint4, t);
    }
}

// ---------------- pass 2: tiled GEMM (identical to R12) ----------------
__global__ __launch_bounds__(512, 4)
void gemm(const uint4* __restrict__ ws, float* __restrict__ out)
{
    __shared__ uint4 ldsT[128 * 16];   // 32 KB  tar panel (A operand, 128 t-rows)
    __shared__ uint4 ldsX[64 * 32];    // 32 KB  f32 epilogue buffer (64 rows x 512B)

    const uint4* wsrc = ws;
    const uint4* wtar = ws + (size_t)NB * S * 16;

    const int blk = blockIdx.x;        // 0..1023 ; round-robin => b == XCD id
    const int b   = blk & 7;
    const int j   = blk >> 3;          // 0..127
    const int ts  = j >> 3;            // 0..15  source tile (128 rows)
    const int tp  = j & 7;             // 0..7   target pair (2 x 128 rows)

    const int tid  = threadIdx.x;
    const int lane = tid & 63;
    const int w    = tid >> 6;
    const int wt   = w & 1;            // 0..1  t-half (64 t-rows)
    const int wsp  = w >> 1;           // 0..3  s-quarter (32 s-rows)
    const int r16  = lane & 15;
    const int kg   = lane >> 4;        // 0..3
    const int swz  = r16 & 7;

    // ---- B operand (src rows) directly into registers, once per block ----
    bf16x8 bregs[2][4];
    #pragma unroll
    for (int n = 0; n < 2; ++n)
        #pragma unroll
        for (int ks = 0; ks < 4; ++ks) {
            const int R = b * S + ts * 128 + wsp * 32 + n * 16 + r16;
            bregs[n][ks] = __builtin_bit_cast(bf16x8, wsrc[(size_t)R * 16 + ((ks * 4 + kg) ^ swz)]);
        }

    // ---- stage first T panel ----
    const uint4* gt0 = wtar + ((size_t)(b * T + tp * 256)) * 16;
    #pragma unroll
    for (int i = 0; i < 4; ++i)
        g2l(gt0 + i * 512 + tid, &ldsT[i * 512 + w * 64]);
    asm volatile("s_waitcnt vmcnt(0)" ::: "memory");
    __builtin_amdgcn_s_barrier();
    __builtin_amdgcn_sched_barrier(0);

    f32x4 acc[4][2];

    #pragma unroll
    for (int tile = 0; tile < 2; ++tile) {
        #pragma unroll
        for (int m = 0; m < 4; ++m)
            #pragma unroll
            for (int n = 0; n < 2; ++n)
                acc[m][n] = f32x4{0.f, 0.f, 0.f, 0.f};

        #pragma unroll
        for (int ks = 0; ks < 4; ++ks) {          // K = 4 * 32
            bf16x8 at[4];
            #pragma unroll
            for (int m = 0; m < 4; ++m) {
                const int rl = wt * 64 + m * 16 + r16;
                at[m] = __builtin_bit_cast(bf16x8, ldsT[rl * 16 + ((ks * 4 + kg) ^ swz)]);
            }
            #pragma unroll
            for (int m = 0; m < 4; ++m)
                #pragma unroll
                for (int n = 0; n < 2; ++n)
                    acc[m][n] = __builtin_amdgcn_mfma_f32_16x16x32_bf16(at[m], bregs[n][ks], acc[m][n], 0, 0, 0);
        }

        if (tile == 0) {
            __syncthreads();                       // all waves done reading ldsT (nothing in flight -> cheap)
            const uint4* gt1 = gt0 + 128 * 16;
            #pragma unroll
            for (int i = 0; i < 4; ++i)            // prefetch next tar panel (4 loads)
                g2l(gt1 + i * 512 + tid, &ldsT[i * 512 + w * 64]);
            __builtin_amdgcn_sched_barrier(0);     // pin: loads issued before stores
        }

        // ---- epilogue: acc -> ldsX (64-row halves) -> 2rows x 512B wave stores ----
        const int ttc = tp * 2 + tile;
        #pragma unroll
        for (int h = 0; h < 2; ++h) {
            if ((wsp >> 1) == h) {                 // waves owning s-rows [h*64, h*64+64)
                #pragma unroll
                for (int m = 0; m < 4; ++m)
                    #pragma unroll
                    for (int n = 0; n < 2; ++n) {
                        const int lrow = (wsp & 1) * 32 + n * 16 + r16;   // 0..63
                        const int col  = wt * 16 + m * 4 + kg;            // 0..31 (f32x4 slots)
                        const f32x4 a = acc[m][n];
                        f32x4 o;
                        o[0] = fmaxf(a[0], 0.f);
                        o[1] = fmaxf(a[1], 0.f);
                        o[2] = fmaxf(a[2], 0.f);
                        o[3] = fmaxf(a[3], 0.f);
                        ldsX[lrow * 32 + (col ^ (lrow & 31))] = __builtin_bit_cast(uint4, o);
                    }
            }
            asm volatile("s_waitcnt lgkmcnt(0)" ::: "memory");   // ds_writes visible
            __builtin_amdgcn_s_barrier();
            __builtin_amdgcn_sched_barrier(0);

            #pragma unroll
            for (int it = 0; it < 4; ++it) {       // 64 rows x 32 uint4 cooperative store
                const int flat = it * 512 + tid;   // 0..2047
                const int row  = flat >> 5;        // 0..63
                const int col  = flat & 31;
                const uint4 v = ldsX[row * 32 + (col ^ (row & 31))];
                float* po = out + ((size_t)(b * S + ts * 128 + h * 64 + row)) * T
                                + (size_t)ttc * 128 + col * 4;
                *(f32x4*)po = __builtin_bit_cast(f32x4, v);
            }

            // ldsX reads done before next half overwrites; stores stay in flight
            asm volatile("s_waitcnt lgkmcnt(0)" ::: "memory");
            if (tile == 0 && h == 1)
                asm volatile("s_waitcnt vmcnt(8)" ::: "memory");  // retire the 4 g2l (8 younger stores ok)
            __builtin_amdgcn_s_barrier();
            __builtin_amdgcn_sched_barrier(0);
        }
    }
}

extern "C" void kernel_launch(void* const* d_in, const int* in_sizes, int n_in,
                              void* d_out, int out_size, void* d_ws, size_t ws_size,
                              hipStream_t stream) {
    const float* src    = (const float*)d_in[0];
    const float* tar    = (const float*)d_in[1];
    const int*   mask_s = (const int*)d_in[2];
    const int*   mask_t = (const int*)d_in[3];
    float*       out    = (float*)d_out;
    uint4*       ws     = (uint4*)d_ws;

    hipLaunchKernelGGL(prep, dim3(256), dim3(512), 0, stream, src, tar, mask_s, mask_t, ws);
    hipLaunchKernelGGL(gemm, dim3(1024), dim3(512), 0, stream, ws, out);
}

// Round 14
// 33.563 us; speedup vs baseline: 1.1198x; 1.0025x over previous
//
#include <hip/hip_runtime.h>
#include <hip/hip_bf16.h>
#include <hip/hip_cooperative_groups.h>

namespace cg = cooperative_groups;

typedef __bf16 bf16x8 __attribute__((ext_vector_type(8)));
typedef float  f32x4  __attribute__((ext_vector_type(4)));

static constexpr int NB = 8;
static constexpr int S  = 2048;
static constexpr int T  = 2048;
static constexpr int D  = 128;

// ws layout: wsrc[16384 rows][16 uint4], wtar[16384 rows][16 uint4]  (8 MB)
// Each row: 128 bf16 (normalized, mask-folded), slot q stored at (q ^ (row&7))
// == the exact LDS image the GEMM wants (global_load_lds copies linearly).

__device__ __forceinline__ void g2l(const uint4* g, uint4* l) {
    __builtin_amdgcn_global_load_lds((const __attribute__((address_space(1))) void*)g,
                                     (__attribute__((address_space(3))) void*)l, 16, 0, 0);
}

// ================= fused cooperative kernel (512 blocks x 512 thr, 48KB LDS) =========
// Phase A: XCD-local prep (block preps batch blk&7 -> dirty-local L2 for its own
// gemm reads). Phase B: grid sync. Phase C: two R13-gemm work items per block.
__global__ __launch_bounds__(512, 4)
void fused(const float* __restrict__ src, const float* __restrict__ tar,
           const int* __restrict__ ms, const int* __restrict__ mt,
           uint4* __restrict__ ws, float* __restrict__ out)
{
    __shared__ uint4 ldsT[128 * 16];   // 32 KB  tar panel
    __shared__ uint4 ldsX[32 * 32];    // 16 KB  f32 epilogue buffer (32 rows x 512B)

    const int tid = threadIdx.x;
    const int blk = blockIdx.x;        // 0..511 ; round-robin => batch == XCD
    const int b   = blk & 7;

    // ---------------- phase A: prep, 8 threads per row ----------------
    {
        const int g   = (blk >> 3) * 512 + tid;    // 0..32767 eighth-rows of batch b
        const int lr  = g >> 3;                    // 0..4095 (src rows then tar rows)
        const int e   = g & 7;                     // 16-float chunk index
        const bool isT = lr >= 2048;
        const int  r  = b * 2048 + (lr & 2047);
        const float* p = (isT ? tar : src) + (size_t)r * D + e * 16;
        const int   mk = (isT ? mt : ms)[r];
        uint4* wp = ws + ((size_t)(isT ? NB * S : 0) + r) * 16;

        float4 v[4];
        float ss = 0.f;
        if (mk) {
            #pragma unroll
            for (int j2 = 0; j2 < 4; ++j2) {
                v[j2] = ((const float4*)p)[j2];
                ss += v[j2].x * v[j2].x + v[j2].y * v[j2].y + v[j2].z * v[j2].z + v[j2].w * v[j2].w;
            }
        } else {
            #pragma unroll
            for (int j2 = 0; j2 < 4; ++j2) v[j2] = float4{0.f, 0.f, 0.f, 0.f};
        }
        ss += __shfl_xor(ss, 1);                   // 8-lane row-group reduce
        ss += __shfl_xor(ss, 2);
        ss += __shfl_xor(ss, 4);
        const float sc = mk ? (1.0f / fmaxf(sqrtf(ss), 1e-12f)) : 0.0f;

        #pragma unroll
        for (int i = 0; i < 2; ++i) {
            const float4 u0 = v[2 * i], u1 = v[2 * i + 1];
            bf16x8 t;
            t[0] = (__bf16)(u0.x * sc); t[1] = (__bf16)(u0.y * sc);
            t[2] = (__bf16)(u0.z * sc); t[3] = (__bf16)(u0.w * sc);
            t[4] = (__bf16)(u1.x * sc); t[5] = (__bf16)(u1.y * sc);
            t[6] = (__bf16)(u1.z * sc); t[7] = (__bf16)(u1.w * sc);
            wp[(e * 2 + i) ^ (r & 7)] = __builtin_bit_cast(uint4, t);
        }
    }

    __threadfence();
    cg::this_grid().sync();

    // ---------------- phase C: two gemm work items ----------------
    const uint4* wsrc = ws;
    const uint4* wtar = ws + (size_t)NB * S * 16;

    const int lane = tid & 63;
    const int w    = tid >> 6;
    const int wt   = w & 1;            // 0..1  t-half (64 t-rows)
    const int wsp  = w >> 1;           // 0..3  s-quarter (32 s-rows)
    const int r16  = lane & 15;
    const int kg   = lane >> 4;        // 0..3
    const int swz  = r16 & 7;

    #pragma unroll
    for (int half = 0; half < 2; ++half) {
        const int j  = (blk >> 3) + half * 64;   // 0..127
        const int ts = j >> 3;                   // 0..15  source tile (128 rows)
        const int tp = j & 7;                    // 0..7   target pair (2 x 128 rows)

        // B operand (src rows) into registers
        bf16x8 bregs[2][4];
        #pragma unroll
        for (int n = 0; n < 2; ++n)
            #pragma unroll
            for (int ks = 0; ks < 4; ++ks) {
                const int R = b * S + ts * 128 + wsp * 32 + n * 16 + r16;
                bregs[n][ks] = __builtin_bit_cast(bf16x8, wsrc[(size_t)R * 16 + ((ks * 4 + kg) ^ swz)]);
            }

        const uint4* gt0 = wtar + ((size_t)(b * T + tp * 256)) * 16;
        #pragma unroll
        for (int i = 0; i < 4; ++i)
            g2l(gt0 + i * 512 + tid, &ldsT[i * 512 + w * 64]);
        asm volatile("s_waitcnt vmcnt(0)" ::: "memory");
        __builtin_amdgcn_s_barrier();
        __builtin_amdgcn_sched_barrier(0);

        f32x4 acc[4][2];

        #pragma unroll
        for (int tile = 0; tile < 2; ++tile) {
            #pragma unroll
            for (int m = 0; m < 4; ++m)
                #pragma unroll
                for (int n = 0; n < 2; ++n)
                    acc[m][n] = f32x4{0.f, 0.f, 0.f, 0.f};

            #pragma unroll
            for (int ks = 0; ks < 4; ++ks) {          // K = 4 * 32
                bf16x8 at[4];
                #pragma unroll
                for (int m = 0; m < 4; ++m) {
                    const int rl = wt * 64 + m * 16 + r16;
                    at[m] = __builtin_bit_cast(bf16x8, ldsT[rl * 16 + ((ks * 4 + kg) ^ swz)]);
                }
                #pragma unroll
                for (int m = 0; m < 4; ++m)
                    #pragma unroll
                    for (int n = 0; n < 2; ++n)
                        acc[m][n] = __builtin_amdgcn_mfma_f32_16x16x32_bf16(at[m], bregs[n][ks], acc[m][n], 0, 0, 0);
            }

            if (tile == 0) {
                __syncthreads();                       // all waves done reading ldsT
                const uint4* gt1 = gt0 + 128 * 16;
                #pragma unroll
                for (int i = 0; i < 4; ++i)            // prefetch next tar panel
                    g2l(gt1 + i * 512 + tid, &ldsT[i * 512 + w * 64]);
                __builtin_amdgcn_sched_barrier(0);     // pin: loads issued before stores
            }

            // epilogue: acc -> ldsX (32-row quarters) -> 512B-contiguous wave stores
            const int ttc = tp * 2 + tile;
            #pragma unroll
            for (int h = 0; h < 4; ++h) {
                if (wsp == h) {                        // waves owning s-rows [h*32, h*32+32)
                    #pragma unroll
                    for (int m = 0; m < 4; ++m)
                        #pragma unroll
                        for (int n = 0; n < 2; ++n) {
                            const int lrow = n * 16 + r16;            // 0..31
                            const int col  = wt * 16 + m * 4 + kg;    // 0..31
                            const f32x4 a = acc[m][n];
                            f32x4 o;
                            o[0] = fmaxf(a[0], 0.f);
                            o[1] = fmaxf(a[1], 0.f);
                            o[2] = fmaxf(a[2], 0.f);
                            o[3] = fmaxf(a[3], 0.f);
                            ldsX[lrow * 32 + (col ^ (lrow & 31))] = __builtin_bit_cast(uint4, o);
                        }
                }
                asm volatile("s_waitcnt lgkmcnt(0)" ::: "memory");
                __builtin_amdgcn_s_barrier();
                __builtin_amdgcn_sched_barrier(0);

                #pragma unroll
                for (int st = 0; st < 2; ++st) {       // 32 rows x 32 uint4 cooperative store
                    const int flat = st * 512 + tid;   // 0..1023
                    const int row  = flat >> 5;        // 0..31
                    const int col  = flat & 31;
                    const uint4 vv = ldsX[row * 32 + (col ^ (row & 31))];
                    float* po = out + ((size_t)(b * S + ts * 128 + h * 32 + row)) * T
                                    + (size_t)ttc * 128 + col * 4;
                    *(f32x4*)po = __builtin_bit_cast(f32x4, vv);
                }

                asm volatile("s_waitcnt lgkmcnt(0)" ::: "memory");
                if (tile == 0 && h == 3)
                    asm volatile("s_waitcnt vmcnt(8)" ::: "memory");  // retire the 4 g2l
                __builtin_amdgcn_s_barrier();
                __builtin_amdgcn_sched_barrier(0);
            }
        }
    }
}

// ================= fallback path: R13 exact (prep 256 + gemm 1024) =================
__global__ __launch_bounds__(512, 2)
void prep(const float* __restrict__ src, const float* __restrict__ tar,
          const int* __restrict__ ms, const int* __restrict__ mt,
          uint4* __restrict__ ws)
{
    const int tid   = threadIdx.x;
    const int p     = blockIdx.x;               // 0..255
    const int b     = p & 7;                    // batch == XCD (round-robin)
    const int chunk = p >> 3;                   // 0..31
    const int lr    = chunk * 128 + (tid >> 2); // 0..4095 batch-local row
    const int q     = tid & 3;
    const bool isT  = lr >= 2048;
    const int  r    = b * 2048 + (lr & 2047);
    const float* pp = (isT ? tar : src) + (size_t)r * D + q * 32;
    const int   mk  = (isT ? mt : ms)[r];
    uint4*      wp  = ws + ((size_t)(isT ? NB * S : 0) + r) * 16;

    float4 v[8];
    float ss = 0.f;
    if (mk) {
        #pragma unroll
        for (int j = 0; j < 8; ++j) {
            v[j] = ((const float4*)pp)[j];
            ss += v[j].x * v[j].x + v[j].y * v[j].y + v[j].z * v[j].z + v[j].w * v[j].w;
        }
    } else {
        #pragma unroll
        for (int j = 0; j < 8; ++j) v[j] = float4{0.f, 0.f, 0.f, 0.f};
    }
    ss += __shfl_xor(ss, 1);
    ss += __shfl_xor(ss, 2);
    const float sc = mk ? (1.0f / fmaxf(sqrtf(ss), 1e-12f)) : 0.0f;

    #pragma unroll
    for (int i = 0; i < 4; ++i) {
        const float4 u0 = v[2 * i], u1 = v[2 * i + 1];
        bf16x8 t;
        t[0] = (__bf16)(u0.x * sc); t[1] = (__bf16)(u0.y * sc);
        t[2] = (__bf16)(u0.z * sc); t[3] = (__bf16)(u0.w * sc);
        t[4] = (__bf16)(u1.x * sc); t[5] = (__bf16)(u1.y * sc);
        t[6] = (__bf16)(u1.z * sc); t[7] = (__bf16)(u1.w * sc);
        wp[(q * 4 + i) ^ (r & 7)] = __builtin_bit_cast(uint4, t);
    }
}

__global__ __launch_bounds__(512, 4)
void gemm(const uint4* __restrict__ ws, float* __restrict__ out)
{
    __shared__ uint4 ldsT[128 * 16];
    __shared__ uint4 ldsX[64 * 32];

    const uint4* wsrc = ws;
    const uint4* wtar = ws + (size_t)NB * S * 16;

    const int blk = blockIdx.x;
    const int b   = blk & 7;
    const int j   = blk >> 3;
    const int ts  = j >> 3;
    const int tp  = j & 7;

    const int tid  = threadIdx.x;
    const int lane = tid & 63;
    const int w    = tid >> 6;
    const int wt   = w & 1;
    const int wsp  = w >> 1;
    const int r16  = lane & 15;
    const int kg   = lane >> 4;
    const int swz  = r16 & 7;

    bf16x8 bregs[2][4];
    #pragma unroll
    for (int n = 0; n < 2; ++n)
        #pragma unroll
        for (int ks = 0; ks < 4; ++ks) {
            const int R = b * S + ts * 128 + wsp * 32 + n * 16 + r16;
            bregs[n][ks] = __builtin_bit_cast(bf16x8, wsrc[(size_t)R * 16 + ((ks * 4 + kg) ^ swz)]);
        }

    const uint4* gt0 = wtar + ((size_t)(b * T + tp * 256)) * 16;
    #pragma unroll
    for (int i = 0; i < 4; ++i)
        g2l(gt0 + i * 512 + tid, &ldsT[i * 512 + w * 64]);
    asm volatile("s_waitcnt vmcnt(0)" ::: "memory");
    __builtin_amdgcn_s_barrier();
    __builtin_amdgcn_sched_barrier(0);

    f32x4 acc[4][2];

    #pragma unroll
    for (int tile = 0; tile < 2; ++tile) {
        #pragma unroll
        for (int m = 0; m < 4; ++m)
            #pragma unroll
            for (int n = 0; n < 2; ++n)
                acc[m][n] = f32x4{0.f, 0.f, 0.f, 0.f};

        #pragma unroll
        for (int ks = 0; ks < 4; ++ks) {
            bf16x8 at[4];
            #pragma unroll
            for (int m = 0; m < 4; ++m) {
                const int rl = wt * 64 + m * 16 + r16;
                at[m] = __builtin_bit_cast(bf16x8, ldsT[rl * 16 + ((ks * 4 + kg) ^ swz)]);
            }
            #pragma unroll
            for (int m = 0; m < 4; ++m)
                #pragma unroll
                for (int n = 0; n < 2; ++n)
                    acc[m][n] = __builtin_amdgcn_mfma_f32_16x16x32_bf16(at[m], bregs[n][ks], acc[m][n], 0, 0, 0);
        }

        if (tile == 0) {
            __syncthreads();
            const uint4* gt1 = gt0 + 128 * 16;
            #pragma unroll
            for (int i = 0; i < 4; ++i)
                g2l(gt1 + i * 512 + tid, &ldsT[i * 512 + w * 64]);
            __builtin_amdgcn_sched_barrier(0);
        }

        const int ttc = tp * 2 + tile;
        #pragma unroll
        for (int h = 0; h < 2; ++h) {
            if ((wsp >> 1) == h) {
                #pragma unroll
                for (int m = 0; m < 4; ++m)
                    #pragma unroll
                    for (int n = 0; n < 2; ++n) {
                        const int lrow = (wsp & 1) * 32 + n * 16 + r16;
                        const int col  = wt * 16 + m * 4 + kg;
                        const f32x4 a = acc[m][n];
                        f32x4 o;
                        o[0] = fmaxf(a[0], 0.f);
                        o[1] = fmaxf(a[1], 0.f);
                        o[2] = fmaxf(a[2], 0.f);
                        o[3] = fmaxf(a[3], 0.f);
                        ldsX[lrow * 32 + (col ^ (lrow & 31))] = __builtin_bit_cast(uint4, o);
                    }
            }
            asm volatile("s_waitcnt lgkmcnt(0)" ::: "memory");
            __builtin_amdgcn_s_barrier();
            __builtin_amdgcn_sched_barrier(0);

            #pragma unroll
            for (int it = 0; it < 4; ++it) {
                const int flat = it * 512 + tid;
                const int row  = flat >> 5;
                const int col  = flat & 31;
                const uint4 v = ldsX[row * 32 + (col ^ (row & 31))];
                float* po = out + ((size_t)(b * S + ts * 128 + h * 64 + row)) * T
                                + (size_t)ttc * 128 + col * 4;
                *(f32x4*)po = __builtin_bit_cast(f32x4, v);
            }

            asm volatile("s_waitcnt lgkmcnt(0)" ::: "memory");
            if (tile == 0 && h == 1)
                asm volatile("s_waitcnt vmcnt(8)" ::: "memory");
            __builtin_amdgcn_s_barrier();
            __builtin_amdgcn_sched_barrier(0);
        }
    }
}

extern "C" void kernel_launch(void* const* d_in, const int* in_sizes, int n_in,
                              void* d_out, int out_size, void* d_ws, size_t ws_size,
                              hipStream_t stream) {
    const float* src    = (const float*)d_in[0];
    const float* tar    = (const float*)d_in[1];
    const int*   mask_s = (const int*)d_in[2];
    const int*   mask_t = (const int*)d_in[3];
    float*       out    = (float*)d_out;
    uint4*       ws     = (uint4*)d_ws;

    // capture-safe host queries; deterministic per-call decision
    int coop = 0;
    hipDeviceGetAttribute(&coop, hipDeviceAttributeCooperativeLaunch, 0);
    int nb = 0;
    if (coop)
        hipOccupancyMaxActiveBlocksPerMultiprocessor(&nb, fused, 512, 0);

    bool launched = false;
    if (coop && nb >= 2) {
        void* args[] = {(void*)&src, (void*)&tar, (void*)&mask_s, (void*)&mask_t,
                        (void*)&ws, (void*)&out};
        launched = (hipLaunchCooperativeKernel((const void*)fused, dim3(512), dim3(512),
                                               args, 0, stream) == hipSuccess);
    }
    if (!launched) {
        hipLaunchKernelGGL(prep, dim3(256), dim3(512), 0, stream, src, tar, mask_s, mask_t, ws);
        hipLaunchKernelGGL(gemm, dim3(1024), dim3(512), 0, stream, ws, out);
    }
}